// Round 14
// baseline (80.816 us; speedup 1.0000x reference)
//
#include <hip/hip_runtime.h>

#define EPSF 1e-7f

typedef unsigned int u32;

// ---- DPP cross-lane helpers (VALU pipe, no DS; verified R2-R13) ----
#define DPPF0(x, ctrl) \
    __int_as_float(__builtin_amdgcn_update_dpp(0, __float_as_int(x), ctrl, 0xF, 0xF, false))

__device__ __forceinline__ float f_rcp(float x) { return __builtin_amdgcn_rcpf(x); }
__device__ __forceinline__ float wave_shr1_f(float x) { return DPPF0(x, 0x138); }

__device__ __forceinline__ float wave_max64(float x) {
    x = fmaxf(x, DPPF0(x, 0x111));   // row_shr:1
    x = fmaxf(x, DPPF0(x, 0x112));   // row_shr:2
    x = fmaxf(x, DPPF0(x, 0x114));   // row_shr:4
    x = fmaxf(x, DPPF0(x, 0x118));   // row_shr:8
    x = fmaxf(x, DPPF0(x, 0x142));   // row_bcast:15
    x = fmaxf(x, DPPF0(x, 0x143));   // row_bcast:31
    return __int_as_float(__builtin_amdgcn_readlane(__float_as_int(x), 63));
}

// pack two fp32 -> bf16x2 word (RNE); unpack = shift / and (verified R13)
__device__ __forceinline__ u32 pack_bf2(float a, float b) {
    u32 ua = __float_as_uint(a), ub = __float_as_uint(b);
    ua += 0x7FFFu + ((ua >> 16) & 1u);
    ub += 0x7FFFu + ((ub >> 16) & 1u);
    return (ua >> 16) | (ub & 0xFFFF0000u);
}

// ---- one CTC step for TWO independent batch rows (A,B) interleaved ----
// q-normalized (R4/R13-verified math). The two rows' chains are independent:
// row B's instructions fill row A's dependency stalls on the in-order wave.
#define STEPQ2(WA_, WB_) do { \
    const u32 wa_ = (WA_), wb_ = (WB_); \
    const float q1a = __uint_as_float(wa_ << 16); \
    const float q3a = __uint_as_float(wa_ & 0xFFFF0000u); \
    const float q1b = __uint_as_float(wb_ << 16); \
    const float q3b = __uint_as_float(wb_ & 0xFFFF0000u); \
    const float n3a = wave_shr1_f(uA3); \
    const float n3b = wave_shr1_f(uB3); \
    const float t1a = fmaf(m1A, n3a, uA0 + uA1); \
    const float t1b = fmaf(m1B, n3b, uB0 + uB1); \
    const float t3a = fmaf(m3A, uA1, uA2 + uA3); \
    const float t3b = fmaf(m3B, uB1, uB2 + uB3); \
    uA4 += uA3; uB4 += uB3; \
    uA2 += uA1; uB2 += uB1; \
    uA3 = t3a * q3a; uB3 = t3b * q3b; \
    uA1 = t1a * q1a; uB1 = t1b * q1b; \
    uA0 += n3a; uB0 += n3b; \
} while (0)

#define SNAPA(RM, LM) do { \
    float mm_ = fmaxf(fmaxf(uA0, uA1), fmaxf(uA2, fmaxf(uA3, uA4))); \
    mm_ = wave_max64(mm_); RM = f_rcp(mm_); LM = __logf(mm_); } while (0)
#define SNAPB(RM, LM) do { \
    float mm_ = fmaxf(fmaxf(uB0, uB1), fmaxf(uB2, fmaxf(uB3, uB4))); \
    mm_ = wave_max64(mm_); RM = f_rcp(mm_); LM = __logf(mm_); } while (0)
#define APPLYA(RM, LM) do { uA0*=RM; uA1*=RM; uA2*=RM; uA3*=RM; uA4*=RM; OA += LM; } while (0)
#define APPLYB(RM, LM) do { uB0*=RM; uB1*=RM; uB2*=RM; uB3*=RM; uB4*=RM; OB += LM; } while (0)

// load one 8-row window of q-words for both rows (lane-linear, conflict-free)
#define LDW2(X, BUF, BASE) do { \
    X##a0 = qbuf[BUF][0][(BASE)+0][lane]; X##a1 = qbuf[BUF][0][(BASE)+1][lane]; \
    X##a2 = qbuf[BUF][0][(BASE)+2][lane]; X##a3 = qbuf[BUF][0][(BASE)+3][lane]; \
    X##a4 = qbuf[BUF][0][(BASE)+4][lane]; X##a5 = qbuf[BUF][0][(BASE)+5][lane]; \
    X##a6 = qbuf[BUF][0][(BASE)+6][lane]; X##a7 = qbuf[BUF][0][(BASE)+7][lane]; \
    X##b0 = qbuf[BUF][1][(BASE)+0][lane]; X##b1 = qbuf[BUF][1][(BASE)+1][lane]; \
    X##b2 = qbuf[BUF][1][(BASE)+2][lane]; X##b3 = qbuf[BUF][1][(BASE)+3][lane]; \
    X##b4 = qbuf[BUF][1][(BASE)+4][lane]; X##b5 = qbuf[BUF][1][(BASE)+5][lane]; \
    X##b6 = qbuf[BUF][1][(BASE)+6][lane]; X##b7 = qbuf[BUF][1][(BASE)+7][lane]; \
} while (0)

// full 8-step window, R4/R13 cadence: apply@2, snap@4, apply@6, snap@8
#define CONS8_2(X) do { \
    STEPQ2(X##a0, X##b0); STEPQ2(X##a1, X##b1); \
    APPLYA(rm1A, lm1A); APPLYB(rm1B, lm1B); \
    STEPQ2(X##a2, X##b2); STEPQ2(X##a3, X##b3); \
    SNAPA(rm2A, lm2A); SNAPB(rm2B, lm2B); \
    STEPQ2(X##a4, X##b4); STEPQ2(X##a5, X##b5); \
    APPLYA(rm2A, lm2A); APPLYB(rm2B, lm2B); \
    STEPQ2(X##a6, X##b6); STEPQ2(X##a7, X##b7); \
    SNAPA(rm1A, lm1A); SNAPB(rm1B, lm1B); \
} while (0)

// chunk-0 first window: rows 1..7 (row 0 is the init), same bounded cadence
#define CONS0_2(X) do { \
    STEPQ2(X##a1, X##b1); STEPQ2(X##a2, X##b2); \
    APPLYA(rm1A, lm1A); APPLYB(rm1B, lm1B); \
    STEPQ2(X##a3, X##b3); STEPQ2(X##a4, X##b4); \
    SNAPA(rm2A, lm2A); SNAPB(rm2B, lm2B); \
    STEPQ2(X##a5, X##b5); STEPQ2(X##a6, X##b6); \
    APPLYA(rm2A, lm2A); APPLYB(rm2B, lm2B); \
    STEPQ2(X##a7, X##b7); \
    SNAPA(rm1A, lm1A); SNAPB(rm1B, lm1B); \
} while (0)

// =====================================================================
// Producer-consumer kernel, T=512/C=128/U=128. One block (4 waves) per
// PAIR of batch rows (2b, 2b+1). 17 phases, one __syncthreads each:
//   wave 0   : scans chunk p-1 (32 steps x 2 rows interleaved) from LDS
//   waves 1-3: pack chunk p -> qbuf[p&1] (scattered gathers + q= p/pb,
//              bf16x2), plus per-wave blank-log partial sums
// Ping-pong LDS: scan reads buf (p-1)&1 while packers fill buf p&1.
// =====================================================================
__global__ __launch_bounds__(256, 1) void ctc_pc512(
        const int* __restrict__ y_true, const float* __restrict__ y_pred,
        float* __restrict__ out) {
    __shared__ u32   qbuf[2][2][32][64];   // 32 KB [buf][row][t][lane]
    __shared__ float blsw[2][4];           // blank-log partials [row][wave]

    const int b    = blockIdx.x;           // rows 2b, 2b+1
    const int tid  = threadIdx.x;
    const int w    = tid >> 6;
    const int lane = tid & 63;
    const float* __restrict__ ypA = y_pred + (size_t)(2 * b)     * (512 * 128);
    const float* __restrict__ ypB = y_pred + (size_t)(2 * b + 1) * (512 * 128);

    const int2 lcA = ((const int2*)(y_true + (size_t)(2 * b)     * 128))[lane];
    const int2 lcB = ((const int2*)(y_true + (size_t)(2 * b + 1) * 128))[lane];
    const int c1A = lcA.x, c3A = lcA.y, c1B = lcB.x, c3B = lcB.y;

    // skip masks (scan wave uses; cheap everywhere)
    const int cpA = __builtin_amdgcn_update_dpp(0, c3A, 0x138, 0xF, 0xF, false);
    const int cpB = __builtin_amdgcn_update_dpp(0, c3B, 0x138, 0xF, 0xF, false);
    const float m1A = (lane > 0 && c1A != cpA) ? 1.f : 0.f;
    const float m3A = (c3A != c1A) ? 1.f : 0.f;
    const float m1B = (lane > 0 && c1B != cpB) ? 1.f : 0.f;
    const float m3B = (c3B != c1B) ? 1.f : 0.f;

    // scan state (wave 0), init from row 0 (exact fp32)
    float uA0 = (lane == 0) ? ypA[127] + EPSF : 0.f;
    float uA1 = (lane == 0) ? ypA[c1A] + EPSF : 0.f;
    float uA2 = 0.f, uA3 = 0.f, uA4 = 0.f;
    float uB0 = (lane == 0) ? ypB[127] + EPSF : 0.f;
    float uB1 = (lane == 0) ? ypB[c1B] + EPSF : 0.f;
    float uB2 = 0.f, uB3 = 0.f, uB4 = 0.f;
    float OA = 0.f, OB = 0.f;
    float rm1A = 1.f, lm1A = 0.f, rm2A = 1.f, lm2A = 0.f;
    float rm1B = 1.f, lm1B = 0.f, rm2B = 1.f, lm2B = 0.f;

    // packer blank-log accumulators (uniform across lanes)
    float blsA = 0.f, blsB = 0.f;

    u32 Pa0, Pa1, Pa2, Pa3, Pa4, Pa5, Pa6, Pa7;
    u32 Pb0, Pb1, Pb2, Pb3, Pb4, Pb5, Pb6, Pb7;
    u32 Qa0, Qa1, Qa2, Qa3, Qa4, Qa5, Qa6, Qa7;
    u32 Qb0, Qb1, Qb2, Qb3, Qb4, Qb5, Qb6, Qb7;

    for (int p = 0; p < 17; ++p) {
        if (w == 0) {
            if (p >= 1) {                       // scan chunk p-1
                const int bufS = (p - 1) & 1;
                LDW2(P, bufS, 0);
                LDW2(Q, bufS, 8);
                if (p == 1) { CONS0_2(P); } else { CONS8_2(P); }
                LDW2(P, bufS, 16);
                CONS8_2(Q);
                LDW2(Q, bufS, 24);
                CONS8_2(P);
                CONS8_2(Q);
            }
        } else {
            if (p <= 15) {                      // pack chunk p
                const int bufP  = p & 1;
                const int tbase = p * 32;
#pragma unroll 3
                for (int i = w - 1; i < 64; i += 3) {
                    const int r  = i >> 5;      // 0 = row A, 1 = row B
                    const int t  = i & 31;
                    const int tg = tbase + t;
                    const float* rowp = (r ? ypB : ypA) + (size_t)tg * 128;
                    const int cc1 = r ? c1B : c1A;
                    const int cc3 = r ? c3B : c3A;
                    const float p1  = rowp[cc1];
                    const float p3  = rowp[cc3];
                    const float pbe = rowp[127] + EPSF;
                    const float rpb = f_rcp(pbe);
                    qbuf[bufP][r][t][lane] =
                        pack_bf2((p1 + EPSF) * rpb, (p3 + EPSF) * rpb);
                    if (tg >= 1) {
                        const float lg = __logf(pbe);
                        if (r) blsB += lg; else blsA += lg;
                    }
                }
            } else if (lane == 0) {             // p == 16: publish partials
                blsw[0][w] = blsA;
                blsw[1][w] = blsB;
            }
        }
        __syncthreads();
    }

    if (w == 0 && lane == 63) {
        const float blsAt = blsw[0][1] + blsw[0][2] + blsw[0][3];
        const float blsBt = blsw[1][1] + blsw[1][2] + blsw[1][3];
        out[2 * b]     = -(OA + blsAt + __logf(uA3 + uA4));
        out[2 * b + 1] = -(OB + blsBt + __logf(uB3 + uB4));
    }
}

// =====================================================================
// Generic fallback (other shapes / odd B), R12-verified.
// =====================================================================
__global__ __launch_bounds__(64, 1) void ctc_scan_generic(
        const int* __restrict__ y_true, const float* __restrict__ y_pred,
        float* __restrict__ out, int T, int C, int U) {
    const int b    = blockIdx.x;
    const int lane = threadIdx.x;
    const int blank = C - 1;
    const float* __restrict__ yp = y_pred + (size_t)b * T * C;

    const int2 lc = ((const int2*)(y_true + (size_t)b * U))[lane];
    const int c1 = lc.x, c3 = lc.y;
    const int cp = __builtin_amdgcn_update_dpp(0, c3, 0x138, 0xF, 0xF, false);
    const float m1 = (lane > 0 && c1 != cp) ? 1.f : 0.f;
    const float m3 = (c3 != c1) ? 1.f : 0.f;

    float u0 = (lane == 0) ? yp[blank] + EPSF : 0.f;
    float u1 = (lane == 0) ? yp[c1] + EPSF : 0.f;
    float u2 = 0.f, u3 = 0.f, u4 = 0.f;
    float O = 0.f;
    float rmA = 1.0f, lmA = 0.0f;
    int kren = 0;

    for (int t = 1; t < T; ++t) {
        const float* row = yp + (size_t)t * C;
        const float pbe = row[blank] + EPSF;
        const float rpb = f_rcp(pbe);
        const float q1  = (row[c1] + EPSF) * rpb;
        const float q3  = (row[c3] + EPSF) * rpb;
        const float n3  = wave_shr1_f(u3);
        const float t1  = fmaf(m1, n3, u0 + u1);
        const float t3  = fmaf(m3, u1, u2 + u3);
        u4 = u4 + u3;
        u3 = t3 * q3;
        u2 = u2 + u1;
        u1 = t1 * q1;
        u0 = u0 + n3;
        O += __logf(pbe);
        if (++kren == 4) {
            float mm_ = fmaxf(fmaxf(u0, u1), fmaxf(u2, fmaxf(u3, u4)));
            mm_ = wave_max64(mm_);
            rmA = f_rcp(mm_);
            lmA = __logf(mm_);
            u0 *= rmA; u1 *= rmA; u2 *= rmA; u3 *= rmA; u4 *= rmA;
            O += lmA;
            kren = 0;
        }
    }
    if (lane == 63) out[b] = -(O + __logf(u3 + u4));
}

extern "C" void kernel_launch(void* const* d_in, const int* in_sizes, int n_in,
                              void* d_out, int out_size, void* d_ws, size_t ws_size,
                              hipStream_t stream) {
    const int*   y_true = (const int*)d_in[0];
    const float* y_pred = (const float*)d_in[1];
    float*       out    = (float*)d_out;

    const int B = out_size;                 // 256
    const int U = in_sizes[0] / B;          // 128
    const int C = 128;                      // classes incl. blank
    const int T = in_sizes[1] / (B * C);    // 512

    if (T == 512 && C == 128 && U == 128 && (B & 1) == 0) {
        ctc_pc512<<<B / 2, 256, 0, stream>>>(y_true, y_pred, out);
    } else {
        ctc_scan_generic<<<B, 64, 0, stream>>>(y_true, y_pred, out, T, C, U);
    }
}